// Round 4
// baseline (112.926 us; speedup 1.0000x reference)
//
#include <hip/hip_runtime.h>
#include <hip/hip_bf16.h>

// B=64, N=M=1024, 3-D points. Chamfer + slot-L2 loss, 3 scalar outputs.
// d^2 matrix computed on MFMA (32x32x16 bf16) via split-bf16 (hi+lo) Gram packing:
//   A-row(point a, c=-2a): [c_hi(3), c_lo(3), c_hi(3), h_hi, h_lo, 1, 1, 0,0,0]
//   B-row(point b):        [b_hi(3), b_hi(3), b_lo(3), 1, 1, h_hi, h_lo, 0,0,0]
//   dot = -2a.b (to ~2^-18) + |a|^2 + |b|^2 = d^2  (abs err ~1e-4)
// Row/col mins accumulate in registers across the swept dimension (no atomics).

#define BATCH 64
#define NPTS 1024
#define PACK_ELEMS (BATCH * NPTS * 16)  // ushorts per pack (2 MB)
// packs in ws: 0=P1A 1=P2A 2=TA 3=P1B 4=P2B 5=TB; then float sums[256]

typedef __attribute__((ext_vector_type(8))) short s16x8;
typedef __attribute__((ext_vector_type(8))) unsigned short u16x8;
typedef __attribute__((ext_vector_type(16))) float f32x16;

__device__ inline unsigned short f2bf(float v) {
    __hip_bfloat16 h = __float2bfloat16(v);
    return *reinterpret_cast<unsigned short*>(&h);
}
__device__ inline float bf2f(unsigned short u) {
    __hip_bfloat16 h = *reinterpret_cast<__hip_bfloat16*>(&u);
    return __bfloat162float(h);
}
__device__ inline float4 min4(float4 a, float4 b) {
    return make_float4(fminf(a.x,b.x), fminf(a.y,b.y), fminf(a.z,b.z), fminf(a.w,b.w));
}

__global__ void zero_kernel(float* out, float* sums) {
    int t = threadIdx.x;
    if (t < 3) out[t] = 0.f;
    sums[t] = 0.f;   // 256 sum slots
}

__global__ __launch_bounds__(256) void pack_kernel(
    const float* __restrict__ p1, const float* __restrict__ p2,
    const float* __restrict__ tg, unsigned short* __restrict__ ws)
{
    int gid = blockIdx.x * 256 + threadIdx.x;    // 0..196607
    int cloud = gid >> 16;                        // 0:P1 1:P2 2:T
    int idx = gid & 65535;                        // b*1024+n
    const float* src = cloud == 0 ? p1 : (cloud == 1 ? p2 : tg);
    float x = src[idx*3+0], y = src[idx*3+1], z = src[idx*3+2];
    float h = fmaf(z, z, fmaf(y, y, x*x));
    unsigned short xh = f2bf(x), yh = f2bf(y), zh = f2bf(z);
    unsigned short xl = f2bf(x - bf2f(xh)), yl = f2bf(y - bf2f(yh)), zl = f2bf(z - bf2f(zh));
    float cx = -2.f*x, cy = -2.f*y, cz = -2.f*z;
    unsigned short cxh = f2bf(cx), cyh = f2bf(cy), czh = f2bf(cz);
    unsigned short cxl = f2bf(cx - bf2f(cxh)), cyl = f2bf(cy - bf2f(cyh)), czl = f2bf(cz - bf2f(czh));
    unsigned short hh = f2bf(h), hl = f2bf(h - bf2f(hh));
    const unsigned short one = 0x3F80;
    u16x8 a0 = {cxh, cyh, czh, cxl, cyl, czl, cxh, cyh};
    u16x8 a1 = {czh, hh, hl, one, one, 0, 0, 0};
    u16x8 b0 = {xh, yh, zh, xh, yh, zh, xl, yl};
    u16x8 b1 = {zl, one, one, hh, hl, 0, 0, 0};
    unsigned short* Adst = ws + (size_t)cloud * PACK_ELEMS + (size_t)idx * 16;
    unsigned short* Bdst = ws + (size_t)(cloud + 3) * PACK_ELEMS + (size_t)idx * 16;
    *(u16x8*)(Adst)     = a0;  *(u16x8*)(Adst + 8) = a1;
    *(u16x8*)(Bdst)     = b0;  *(u16x8*)(Bdst + 8) = b1;
}

// ---- shared tail: scratch transpose + reduce + atomic ----
// scr layout: [wave][cloud][32 rows][36 floats]
__device__ inline void reduce_and_add(float* scr, float rm1[16], float rm2[16],
                                      int w, int lane, float* dst0, float* dst1)
{
    int c = lane & 31, q = lane >> 5;
    #pragma unroll
    for (int r = 0; r < 16; ++r) {
        int R = (r & 3) + 8 * (r >> 2) + 4 * q;
        scr[((w*2 + 0)*32 + R)*36 + c] = rm1[r];
        scr[((w*2 + 1)*32 + R)*36 + c] = rm2[r];
    }
    int cl = q, row = c;
    const float* pr = &scr[((w*2 + cl)*32 + row)*36];
    float4 v0 = *(const float4*)(pr+0),  v1 = *(const float4*)(pr+4);
    float4 v2 = *(const float4*)(pr+8),  v3 = *(const float4*)(pr+12);
    float4 v4 = *(const float4*)(pr+16), v5 = *(const float4*)(pr+20);
    float4 v6 = *(const float4*)(pr+24), v7 = *(const float4*)(pr+28);
    float4 a = min4(min4(v0, v1), min4(v2, v3));
    float4 bq = min4(min4(v4, v5), min4(v6, v7));
    a = min4(a, bq);
    float m = fminf(fminf(a.x, a.y), fminf(a.z, a.w));
    float d = sqrtf(fmaxf(m, 0.f));
    #pragma unroll
    for (int s = 1; s < 32; s <<= 1) d += __shfl_xor(d, s);
    if (lane == 0)  atomicAdd(dst0, d);
    if (lane == 32) atomicAdd(dst1, d);
}

// Row pass: waves own 32 pred rows (P1,P2 A-frags), sweep T (B-side).
__global__ __launch_bounds__(256) void row_pass(
    const unsigned short* __restrict__ ws, float* __restrict__ sums)
{
    __shared__ __align__(16) unsigned char smem[40960];
    unsigned short* T_lds = (unsigned short*)smem;           // TB pack, full batch (32 KB)
    unsigned short* A_lds = (unsigned short*)(smem + 32768); // P1A,P2A 128 rows (8 KB)
    float* scr = (float*)smem;                               // reused after sweep

    int b = blockIdx.x >> 3, chunk = blockIdx.x & 7;
    int tid = threadIdx.x;
    const unsigned short* TB  = ws + (size_t)5*PACK_ELEMS + (size_t)b*NPTS*16;
    const unsigned short* P1A = ws + (size_t)0*PACK_ELEMS + (size_t)(b*NPTS + chunk*128)*16;
    const unsigned short* P2A = ws + (size_t)1*PACK_ELEMS + (size_t)(b*NPTS + chunk*128)*16;

    for (int i = tid; i < 2048; i += 256)
        *(u16x8*)(T_lds + i*8) = *(const u16x8*)(TB + i*8);
    for (int i = tid; i < 512; i += 256) {
        int cl = i >> 8, j = i & 255;
        *(u16x8*)(A_lds + cl*2048 + j*8) = *(const u16x8*)((cl ? P2A : P1A) + j*8);
    }
    __syncthreads();

    int lane = tid & 63, w = tid >> 6;
    int c = lane & 31, q = lane >> 5;
    s16x8 a1 = *(s16x8*)(A_lds + 0*2048 + (w*32 + c)*16 + q*8);
    s16x8 a2 = *(s16x8*)(A_lds + 1*2048 + (w*32 + c)*16 + q*8);

    f32x16 zero = {};
    float rm1[16], rm2[16];
    #pragma unroll
    for (int r = 0; r < 16; ++r) { rm1[r] = 3e38f; rm2[r] = 3e38f; }

    const unsigned short* Tb = T_lds + c*16 + q*8;
    #pragma unroll 1
    for (int mt = 0; mt < 32; mt += 2) {
        s16x8 bf0 = *(const s16x8*)(Tb + mt*512);
        s16x8 bf1 = *(const s16x8*)(Tb + mt*512 + 512);
        f32x16 acc10 = __builtin_amdgcn_mfma_f32_32x32x16_bf16(a1, bf0, zero, 0, 0, 0);
        f32x16 acc20 = __builtin_amdgcn_mfma_f32_32x32x16_bf16(a2, bf0, zero, 0, 0, 0);
        f32x16 acc11 = __builtin_amdgcn_mfma_f32_32x32x16_bf16(a1, bf1, zero, 0, 0, 0);
        f32x16 acc21 = __builtin_amdgcn_mfma_f32_32x32x16_bf16(a2, bf1, zero, 0, 0, 0);
        #pragma unroll
        for (int r = 0; r < 16; ++r) {
            rm1[r] = fminf(rm1[r], fminf(acc10[r], acc11[r]));
            rm2[r] = fminf(rm2[r], fminf(acc20[r], acc21[r]));
        }
    }
    __syncthreads();   // everyone done reading T_lds/A_lds before scratch reuse
    reduce_and_add(scr, rm1, rm2, w, lane, &sums[b*2+0], &sums[b*2+1]);
}

// Col pass: waves own 32 target rows (TA A-frag), sweep P1B,P2B (B-side).
__global__ __launch_bounds__(256) void col_pass(
    const unsigned short* __restrict__ ws, float* __restrict__ sums)
{
    __shared__ __align__(16) unsigned char smem[69632];
    unsigned short* P1_lds = (unsigned short*)smem;            // 32 KB
    unsigned short* P2_lds = (unsigned short*)(smem + 32768);  // 32 KB
    unsigned short* T_ldsA = (unsigned short*)(smem + 65536);  // 4 KB
    float* scr = (float*)smem;

    int b = blockIdx.x >> 3, chunk = blockIdx.x & 7;
    int tid = threadIdx.x;
    const unsigned short* P1B = ws + (size_t)3*PACK_ELEMS + (size_t)b*NPTS*16;
    const unsigned short* P2B = ws + (size_t)4*PACK_ELEMS + (size_t)b*NPTS*16;
    const unsigned short* TA  = ws + (size_t)2*PACK_ELEMS + (size_t)(b*NPTS + chunk*128)*16;

    for (int i = tid; i < 2048; i += 256) {
        *(u16x8*)(P1_lds + i*8) = *(const u16x8*)(P1B + i*8);
        *(u16x8*)(P2_lds + i*8) = *(const u16x8*)(P2B + i*8);
    }
    if (tid < 256) {
        *(u16x8*)(T_ldsA + tid*8) = *(const u16x8*)(TA + tid*8);
    }
    __syncthreads();

    int lane = tid & 63, w = tid >> 6;
    int c = lane & 31, q = lane >> 5;
    s16x8 at = *(s16x8*)(T_ldsA + (w*32 + c)*16 + q*8);

    f32x16 zero = {};
    float rm1[16], rm2[16];
    #pragma unroll
    for (int r = 0; r < 16; ++r) { rm1[r] = 3e38f; rm2[r] = 3e38f; }

    const unsigned short* q1 = P1_lds + c*16 + q*8;
    const unsigned short* q2 = P2_lds + c*16 + q*8;
    #pragma unroll 1
    for (int nt = 0; nt < 32; nt += 2) {
        s16x8 b10 = *(const s16x8*)(q1 + nt*512);
        s16x8 b11 = *(const s16x8*)(q1 + nt*512 + 512);
        s16x8 b20 = *(const s16x8*)(q2 + nt*512);
        s16x8 b21 = *(const s16x8*)(q2 + nt*512 + 512);
        f32x16 acc10 = __builtin_amdgcn_mfma_f32_32x32x16_bf16(at, b10, zero, 0, 0, 0);
        f32x16 acc11 = __builtin_amdgcn_mfma_f32_32x32x16_bf16(at, b11, zero, 0, 0, 0);
        f32x16 acc20 = __builtin_amdgcn_mfma_f32_32x32x16_bf16(at, b20, zero, 0, 0, 0);
        f32x16 acc21 = __builtin_amdgcn_mfma_f32_32x32x16_bf16(at, b21, zero, 0, 0, 0);
        #pragma unroll
        for (int r = 0; r < 16; ++r) {
            rm1[r] = fminf(rm1[r], fminf(acc10[r], acc11[r]));
            rm2[r] = fminf(rm2[r], fminf(acc20[r], acc21[r]));
        }
    }
    __syncthreads();
    reduce_and_add(scr, rm1, rm2, w, lane, &sums[b*2+0], &sums[b*2+1]);
}

__global__ __launch_bounds__(256) void finalize_kernel(
    const float* __restrict__ p1, const float* __restrict__ p2,
    const float* __restrict__ tg, const float* __restrict__ flag1,
    const float* __restrict__ flag2, const float* __restrict__ symf,
    const float* __restrict__ sums, float* __restrict__ out)
{
    int b = blockIdx.x, tid = threadIdx.x;
    float e1 = 0.f, e2 = 0.f;
    for (int n = tid; n < NPTS; n += 256) {
        int base = (b*NPTS + n)*3;
        float tx = tg[base], ty = tg[base+1], tz = tg[base+2];
        float dx = p1[base]-tx, dy = p1[base+1]-ty, dz = p1[base+2]-tz;
        e1 += sqrtf(fmaf(dz, dz, fmaf(dy, dy, dx*dx)));
        dx = p2[base]-tx; dy = p2[base+1]-ty; dz = p2[base+2]-tz;
        e2 += sqrtf(fmaf(dz, dz, fmaf(dy, dy, dx*dx)));
    }
    __shared__ float red[8];
    #pragma unroll
    for (int s = 32; s > 0; s >>= 1) { e1 += __shfl_down(e1, s); e2 += __shfl_down(e2, s); }
    int wv = tid >> 6, ln = tid & 63;
    if (ln == 0) { red[wv*2] = e1; red[wv*2+1] = e2; }
    __syncthreads();
    if (tid == 0) {
        float E1 = red[0]+red[2]+red[4]+red[6];
        float E2 = red[1]+red[3]+red[5]+red[7];
        const float inv = 1.f / (float)NPTS;
        float ch1 = 0.5f*(sums[b*2+0] + sums[128 + b*2+0])*inv;
        float ch2 = 0.5f*(sums[b*2+1] + sums[128 + b*2+1])*inv;
        float sf = symf[b];
        float l1 = flag1[b]*(sf*ch1 + (1.f-sf)*E1*inv);
        float l2 = flag2[b]*(sf*ch2 + (1.f-sf)*E2*inv);
        const float s = 1.f / (float)BATCH;
        atomicAdd(&out[0], (l1+l2)*s);
        atomicAdd(&out[1], l1*s);
        atomicAdd(&out[2], l2*s);
    }
}

extern "C" void kernel_launch(void* const* d_in, const int* in_sizes, int n_in,
                              void* d_out, int out_size, void* d_ws, size_t ws_size,
                              hipStream_t stream) {
    const float* p1 = (const float*)d_in[0];
    const float* p2 = (const float*)d_in[1];
    const float* tg = (const float*)d_in[2];
    const float* f1 = (const float*)d_in[3];
    const float* f2 = (const float*)d_in[4];
    const float* sf = (const float*)d_in[5];
    float* out = (float*)d_out;
    unsigned short* pack = (unsigned short*)d_ws;
    float* sums = (float*)(pack + (size_t)6 * PACK_ELEMS);   // 256 floats

    zero_kernel<<<1, 256, 0, stream>>>(out, sums);
    pack_kernel<<<768, 256, 0, stream>>>(p1, p2, tg, pack);
    row_pass<<<BATCH*8, 256, 0, stream>>>(pack, sums);          // sums[0..127]
    col_pass<<<BATCH*8, 256, 0, stream>>>(pack, sums + 128);    // sums[128..255]
    finalize_kernel<<<BATCH, 256, 0, stream>>>(p1, p2, tg, f1, f2, sf, sums, out);
}

// Round 5
// 83.817 us; speedup vs baseline: 1.3473x; 1.3473x over previous
//
#include <hip/hip_runtime.h>
#include <hip/hip_bf16.h>

// B=64, N=M=1024, 3-D points. Fused single-kernel Chamfer + slot-L2 loss.
// d^2 via MFMA 32x32x16 bf16 split-bf16 Gram packing (validated R4, absmax 0.0):
//   A(point a, c=-2a): [c_hi3, c_lo3, c_hi3, h_hi, h_lo, 1, 1, 0,0,0]
//   B(point b):        [b_hi3, b_hi3, b_lo3, 1, 1, h_hi, h_lo, 0,0,0]
//   dot = |a|^2 + |b|^2 - 2a.b  (abs err ~1e-4)
// Block = (batch, quarter): 16 waves; w<8 row-dir (pred tiles x all T),
// w>=8 col-dir (target tiles x all P1/P2). Full sweep per wave -> reg-local min.

#define BATCH 64
#define NPTS 1024

typedef __attribute__((ext_vector_type(8))) short s16x8;
typedef __attribute__((ext_vector_type(8))) unsigned short u16x8;
typedef __attribute__((ext_vector_type(16))) float f32x16;

__device__ inline unsigned short f2bf(float v) {
    __hip_bfloat16 h = __float2bfloat16(v);
    return *reinterpret_cast<unsigned short*>(&h);
}
__device__ inline float bf2f(unsigned short u) {
    __hip_bfloat16 h = *reinterpret_cast<__hip_bfloat16*>(&u);
    return __bfloat162float(h);
}

__device__ inline void pack_ab(float x, float y, float z,
                               u16x8& a0, u16x8& a1, u16x8& b0, u16x8& b1) {
    float h = fmaf(z, z, fmaf(y, y, x*x));
    unsigned short xh = f2bf(x), yh = f2bf(y), zh = f2bf(z);
    unsigned short xl = f2bf(x - bf2f(xh)), yl = f2bf(y - bf2f(yh)), zl = f2bf(z - bf2f(zh));
    float cx = -2.f*x, cy = -2.f*y, cz = -2.f*z;
    unsigned short cxh = f2bf(cx), cyh = f2bf(cy), czh = f2bf(cz);
    unsigned short cxl = f2bf(cx - bf2f(cxh)), cyl = f2bf(cy - bf2f(cyh)), czl = f2bf(cz - bf2f(czh));
    unsigned short hh = f2bf(h), hl = f2bf(h - bf2f(hh));
    const unsigned short one = 0x3F80;
    a0 = u16x8{cxh, cyh, czh, cxl, cyl, czl, cxh, cyh};
    a1 = u16x8{czh, hh, hl, one, one, 0, 0, 0};
    b0 = u16x8{xh, yh, zh, xh, yh, zh, xl, yl};
    b1 = u16x8{zl, one, one, hh, hl, 0, 0, 0};
}

__global__ void zero_kernel(float* out) {
    if (threadIdx.x < 3) out[threadIdx.x] = 0.0f;
}

// ushort offsets into the big LDS block (layout [tile][K-half][row][8] per cloud)
#define TB_OFF   0        // 16384 ushorts (32 KB): target B-pack, full batch
#define P1B_OFF  16384    // 32 KB
#define P2B_OFF  32768    // 32 KB
#define A1_OFF   49152    // 4096 ushorts (8 KB): P1 A-pack, owned quarter
#define A2_OFF   53248
#define AT_OFF   57344
#define LDS_USH  61440    // 120 KB total

// register-halving min-fold over the 32-lane col group, then sqrt + 64-lane sum.
// Returns 2 x (sum over this wave's 32 rows of sqrt(max(min,0))).
__device__ inline float fold_sum(float v[16], int lane) {
    // mask 1: 16 -> 8
    {
        const bool up = lane & 1;
        #pragma unroll
        for (int k = 0; k < 8; ++k) {
            float send = up ? v[k] : v[k+8];
            float recv = __shfl_xor(send, 1);
            v[k] = fminf(up ? v[k+8] : v[k], recv);
        }
    }
    {   // mask 2: 8 -> 4
        const bool up = lane & 2;
        #pragma unroll
        for (int k = 0; k < 4; ++k) {
            float send = up ? v[k] : v[k+4];
            float recv = __shfl_xor(send, 2);
            v[k] = fminf(up ? v[k+4] : v[k], recv);
        }
    }
    {   // mask 4: 4 -> 2
        const bool up = lane & 4;
        #pragma unroll
        for (int k = 0; k < 2; ++k) {
            float send = up ? v[k] : v[k+2];
            float recv = __shfl_xor(send, 4);
            v[k] = fminf(up ? v[k+2] : v[k], recv);
        }
    }
    {   // mask 8: 2 -> 1
        const bool up = lane & 8;
        float send = up ? v[0] : v[1];
        float recv = __shfl_xor(send, 8);
        v[0] = fminf(up ? v[1] : v[0], recv);
    }
    // mask 16: merge the two 16-lane halves (same row each side)
    v[0] = fminf(v[0], __shfl_xor(v[0], 16));
    float d = sqrtf(fmaxf(v[0], 0.f));
    #pragma unroll
    for (int mask = 1; mask <= 32; mask <<= 1) d += __shfl_xor(d, mask);
    return d;   // each row counted twice
}

__global__ __launch_bounds__(1024) void chamfer_main(
    const float* __restrict__ p1g, const float* __restrict__ p2g,
    const float* __restrict__ tgg, const float* __restrict__ flag1,
    const float* __restrict__ flag2, const float* __restrict__ symf,
    float* __restrict__ out)
{
    __shared__ __align__(16) unsigned short lds[LDS_USH];
    __shared__ float wsum[16][2];
    __shared__ float esum[16][2];

    const int b = blockIdx.x >> 2, chunk = blockIdx.x & 3;
    const int tid = threadIdx.x;
    const int lane = tid & 63, w = tid >> 6;
    const int c = lane & 31, q = lane >> 5;

    // ---- load + pack into LDS ----
    const size_t base = (size_t)b * (NPTS*3) + (size_t)tid * 3;
    const float x1 = p1g[base], y1 = p1g[base+1], z1 = p1g[base+2];
    const float x2 = p2g[base], y2 = p2g[base+1], z2 = p2g[base+2];
    const float xt = tgg[base], yt = tgg[base+1], zt = tgg[base+2];

    const int tile = tid >> 5, r = tid & 31;
    const int bo = tile * 512 + r * 8;          // half0; half1 = +256
    u16x8 a0, a1, b0, b1;
    pack_ab(x1, y1, z1, a0, a1, b0, b1);
    *(u16x8*)(lds + P1B_OFF + bo)       = b0;
    *(u16x8*)(lds + P1B_OFF + bo + 256) = b1;
    u16x8 A1a0 = a0, A1a1 = a1;
    pack_ab(x2, y2, z2, a0, a1, b0, b1);
    *(u16x8*)(lds + P2B_OFF + bo)       = b0;
    *(u16x8*)(lds + P2B_OFF + bo + 256) = b1;
    u16x8 A2a0 = a0, A2a1 = a1;
    pack_ab(xt, yt, zt, a0, a1, b0, b1);
    *(u16x8*)(lds + TB_OFF + bo)        = b0;
    *(u16x8*)(lds + TB_OFF + bo + 256)  = b1;

    float e1 = 0.f, e2 = 0.f;
    if ((tid >> 8) == chunk) {
        const int j = tid - (chunk << 8);
        const int ao = (j >> 5) * 512 + (j & 31) * 8;
        *(u16x8*)(lds + A1_OFF + ao)       = A1a0;
        *(u16x8*)(lds + A1_OFF + ao + 256) = A1a1;
        *(u16x8*)(lds + A2_OFF + ao)       = A2a0;
        *(u16x8*)(lds + A2_OFF + ao + 256) = A2a1;
        *(u16x8*)(lds + AT_OFF + ao)       = a0;
        *(u16x8*)(lds + AT_OFF + ao + 256) = a1;
        float dx = x1 - xt, dy = y1 - yt, dz = z1 - zt;
        e1 = sqrtf(fmaf(dz, dz, fmaf(dy, dy, dx*dx)));
        dx = x2 - xt; dy = y2 - yt; dz = z2 - zt;
        e2 = sqrtf(fmaf(dz, dz, fmaf(dy, dy, dx*dx)));
    }
    __syncthreads();

    // ---- MFMA sweep: full opposite cloud, min in registers ----
    float rm1[16], rm2[16];
    #pragma unroll
    for (int i = 0; i < 16; ++i) { rm1[i] = 3e38f; rm2[i] = 3e38f; }
    const f32x16 zacc = {};
    const int fo = q * 256 + c * 8;   // frag offset within a tile

    if (w < 8) {
        // row-dir: owned pred row-tile w (both clouds), sweep TB
        const s16x8 fa1 = *(const s16x8*)(lds + A1_OFF + w*512 + fo);
        const s16x8 fa2 = *(const s16x8*)(lds + A2_OFF + w*512 + fo);
        const unsigned short* TBp = lds + TB_OFF + fo;
        #pragma unroll 1
        for (int t = 0; t < 32; t += 2) {
            const s16x8 bb0 = *(const s16x8*)(TBp + t*512);
            const s16x8 bb1 = *(const s16x8*)(TBp + t*512 + 512);
            f32x16 u0 = __builtin_amdgcn_mfma_f32_32x32x16_bf16(fa1, bb0, zacc, 0, 0, 0);
            f32x16 u1 = __builtin_amdgcn_mfma_f32_32x32x16_bf16(fa1, bb1, zacc, 0, 0, 0);
            #pragma unroll
            for (int i = 0; i < 16; ++i) rm1[i] = fminf(fminf(u0[i], u1[i]), rm1[i]);
            u0 = __builtin_amdgcn_mfma_f32_32x32x16_bf16(fa2, bb0, zacc, 0, 0, 0);
            u1 = __builtin_amdgcn_mfma_f32_32x32x16_bf16(fa2, bb1, zacc, 0, 0, 0);
            #pragma unroll
            for (int i = 0; i < 16; ++i) rm2[i] = fminf(fminf(u0[i], u1[i]), rm2[i]);
        }
    } else {
        // col-dir: owned target row-tile (w-8), sweep P1B and P2B
        const s16x8 fat = *(const s16x8*)(lds + AT_OFF + (w-8)*512 + fo);
        const unsigned short* Q1p = lds + P1B_OFF + fo;
        const unsigned short* Q2p = lds + P2B_OFF + fo;
        #pragma unroll 1
        for (int t = 0; t < 32; t += 2) {
            s16x8 bb0 = *(const s16x8*)(Q1p + t*512);
            s16x8 bb1 = *(const s16x8*)(Q1p + t*512 + 512);
            f32x16 u0 = __builtin_amdgcn_mfma_f32_32x32x16_bf16(fat, bb0, zacc, 0, 0, 0);
            f32x16 u1 = __builtin_amdgcn_mfma_f32_32x32x16_bf16(fat, bb1, zacc, 0, 0, 0);
            #pragma unroll
            for (int i = 0; i < 16; ++i) rm1[i] = fminf(fminf(u0[i], u1[i]), rm1[i]);
            bb0 = *(const s16x8*)(Q2p + t*512);
            bb1 = *(const s16x8*)(Q2p + t*512 + 512);
            u0 = __builtin_amdgcn_mfma_f32_32x32x16_bf16(fat, bb0, zacc, 0, 0, 0);
            u1 = __builtin_amdgcn_mfma_f32_32x32x16_bf16(fat, bb1, zacc, 0, 0, 0);
            #pragma unroll
            for (int i = 0; i < 16; ++i) rm2[i] = fminf(fminf(u0[i], u1[i]), rm2[i]);
        }
    }

    // ---- reduce ----
    const float s1 = fold_sum(rm1, lane);   // 2x sum of sqrt(min) over wave's 32 rows
    const float s2 = fold_sum(rm2, lane);
    #pragma unroll
    for (int mask = 1; mask <= 32; mask <<= 1) {
        e1 += __shfl_xor(e1, mask);
        e2 += __shfl_xor(e2, mask);
    }
    if (lane == 0) {
        wsum[w][0] = s1; wsum[w][1] = s2;
        esum[w][0] = e1; esum[w][1] = e2;
    }
    __syncthreads();

    if (tid == 0) {
        float rowS1 = 0.f, rowS2 = 0.f, colS1 = 0.f, colS2 = 0.f, E1 = 0.f, E2 = 0.f;
        #pragma unroll
        for (int k = 0; k < 8; ++k)  { rowS1 += wsum[k][0]; rowS2 += wsum[k][1]; }
        #pragma unroll
        for (int k = 8; k < 16; ++k) { colS1 += wsum[k][0]; colS2 += wsum[k][1]; }
        #pragma unroll
        for (int k = 0; k < 16; ++k) { E1 += esum[k][0]; E2 += esum[k][1]; }
        // fold_sum returns 2x the row sum -> 0.5; chamfer bidirectional avg -> 0.5
        const float ch1 = 0.5f * (0.5f * rowS1 + 0.5f * colS1);
        const float ch2 = 0.5f * (0.5f * rowS2 + 0.5f * colS2);
        const float sf = symf[b];
        const float inv = 1.f / (float)NPTS;
        const float l1 = flag1[b] * (sf * ch1 + (1.f - sf) * E1) * inv;
        const float l2 = flag2[b] * (sf * ch2 + (1.f - sf) * E2) * inv;
        const float s = 1.f / (float)BATCH;
        atomicAdd(&out[0], (l1 + l2) * s);
        atomicAdd(&out[1], l1 * s);
        atomicAdd(&out[2], l2 * s);
    }
}

extern "C" void kernel_launch(void* const* d_in, const int* in_sizes, int n_in,
                              void* d_out, int out_size, void* d_ws, size_t ws_size,
                              hipStream_t stream) {
    const float* p1 = (const float*)d_in[0];
    const float* p2 = (const float*)d_in[1];
    const float* tg = (const float*)d_in[2];
    const float* f1 = (const float*)d_in[3];
    const float* f2 = (const float*)d_in[4];
    const float* sf = (const float*)d_in[5];
    float* out = (float*)d_out;

    zero_kernel<<<1, 64, 0, stream>>>(out);
    chamfer_main<<<BATCH * 4, 1024, 0, stream>>>(p1, p2, tg, f1, f2, sf, out);
}

// Round 6
// 76.213 us; speedup vs baseline: 1.4817x; 1.0998x over previous
//
#include <hip/hip_runtime.h>
#include <hip/hip_bf16.h>

// B=64, N=M=1024, 3-D. Chamfer + slot-L2 loss, 3 scalars.
// d^2 on MFMA 32x32x16 bf16, split-bf16 Gram pack (validated R4/R5, absmax 0.0):
//   A(point a, c=-2a): [c_hi3, c_lo3, c_hi3, h_hi, h_lo, 1, 1, 0,0,0]
//   B(point b):        [b_hi3, b_hi3, b_lo3, 1, 1, h_hi, h_lo, 0,0,0]
// Grid = 4 jobs x 64 batches x 4 quarters; each block: 256 rows of X vs all 1024 of Y.
// jobs: 0: P1 rows vs T | 1: P2 vs T | 2: T vs P1 | 3: T vs P2.
// Block partials -> d_ws slots; 1-wave finalize writes out[0..2] (no atomics/zeroing).

#define BATCH 64
#define NPTS 1024

typedef __attribute__((ext_vector_type(8))) short s16x8;
typedef __attribute__((ext_vector_type(8))) unsigned short u16x8;
typedef __attribute__((ext_vector_type(16))) float f32x16;

__device__ inline unsigned short f2bf(float v) {
    __hip_bfloat16 h = __float2bfloat16(v);
    return *reinterpret_cast<unsigned short*>(&h);
}
__device__ inline float bf2f(unsigned short u) {
    __hip_bfloat16 h = *reinterpret_cast<__hip_bfloat16*>(&u);
    return __bfloat162float(h);
}

__device__ inline void pack_ab(float x, float y, float z,
                               u16x8& a0, u16x8& a1, u16x8& b0, u16x8& b1) {
    float h = fmaf(z, z, fmaf(y, y, x*x));
    unsigned short xh = f2bf(x), yh = f2bf(y), zh = f2bf(z);
    unsigned short xl = f2bf(x - bf2f(xh)), yl = f2bf(y - bf2f(yh)), zl = f2bf(z - bf2f(zh));
    float cx = -2.f*x, cy = -2.f*y, cz = -2.f*z;
    unsigned short cxh = f2bf(cx), cyh = f2bf(cy), czh = f2bf(cz);
    unsigned short cxl = f2bf(cx - bf2f(cxh)), cyl = f2bf(cy - bf2f(cyh)), czl = f2bf(cz - bf2f(czh));
    unsigned short hh = f2bf(h), hl = f2bf(h - bf2f(hh));
    const unsigned short one = 0x3F80;
    a0 = u16x8{cxh, cyh, czh, cxl, cyl, czl, cxh, cyh};
    a1 = u16x8{czh, hh, hl, one, one, 0, 0, 0};
    b0 = u16x8{xh, yh, zh, xh, yh, zh, xl, yl};
    b1 = u16x8{zl, one, one, hh, hl, 0, 0, 0};
}

// Register-halving min-fold over 32-col group, then sqrt + full-wave sum.
// Returns 2x (sum over the wave's 32 rows of sqrt(max(min,0))). Validated R5.
__device__ inline float fold_sum(float v[16], int lane) {
    {
        const bool up = lane & 1;
        #pragma unroll
        for (int k = 0; k < 8; ++k) {
            float send = up ? v[k] : v[k+8];
            float recv = __shfl_xor(send, 1);
            v[k] = fminf(up ? v[k+8] : v[k], recv);
        }
    }
    {
        const bool up = lane & 2;
        #pragma unroll
        for (int k = 0; k < 4; ++k) {
            float send = up ? v[k] : v[k+4];
            float recv = __shfl_xor(send, 2);
            v[k] = fminf(up ? v[k+4] : v[k], recv);
        }
    }
    {
        const bool up = lane & 4;
        #pragma unroll
        for (int k = 0; k < 2; ++k) {
            float send = up ? v[k] : v[k+2];
            float recv = __shfl_xor(send, 4);
            v[k] = fminf(up ? v[k+2] : v[k], recv);
        }
    }
    {
        const bool up = lane & 8;
        float send = up ? v[0] : v[1];
        float recv = __shfl_xor(send, 8);
        v[0] = fminf(up ? v[1] : v[0], recv);
    }
    v[0] = fminf(v[0], __shfl_xor(v[0], 16));
    float d = sqrtf(fmaxf(v[0], 0.f));
    #pragma unroll
    for (int mask = 1; mask <= 32; mask <<= 1) d += __shfl_xor(d, mask);
    return d;   // each row counted twice
}

__global__ __launch_bounds__(512) void pass_kernel(
    const float* __restrict__ p1, const float* __restrict__ p2,
    const float* __restrict__ tg, float* __restrict__ ws)
{
    __shared__ __align__(16) unsigned short ybuf[16384];  // 32 KB: Y B-pack, whole batch
    __shared__ __align__(16) unsigned short abuf[4096];   // 8 KB: X A-pack, owned quarter
    __shared__ float red[8];
    __shared__ float redE[8];

    const int bid = blockIdx.x;
    const int j = bid >> 8, b = (bid >> 2) & 63, qt = bid & 3;
    const int tid = threadIdx.x;

    const float* __restrict__ X = (j == 0) ? p1 : (j == 1) ? p2 : tg;
    const float* __restrict__ Y = (j == 2) ? p1 : (j == 3) ? p2 : tg;

    // pack Y (B-side): 2 points per thread
    #pragma unroll
    for (int ii = 0; ii < 2; ++ii) {
        const int i = tid + ii * 512;
        const size_t g = ((size_t)b * NPTS + i) * 3;
        float x = Y[g], y = Y[g+1], z = Y[g+2];
        u16x8 a0, a1, b0, b1;
        pack_ab(x, y, z, a0, a1, b0, b1);
        const int off = (i >> 5) * 512 + (i & 31) * 8;
        *(u16x8*)(ybuf + off)       = b0;
        *(u16x8*)(ybuf + off + 256) = b1;
    }
    // pack X quarter (A-side) + slot-L2 term (jobs 0,1 only)
    float e = 0.f;
    if (tid < 256) {
        const int i = qt * 256 + tid;
        const size_t g = ((size_t)b * NPTS + i) * 3;
        float x = X[g], y = X[g+1], z = X[g+2];
        u16x8 a0, a1, b0, b1;
        pack_ab(x, y, z, a0, a1, b0, b1);
        const int off = (tid >> 5) * 512 + (tid & 31) * 8;
        *(u16x8*)(abuf + off)       = a0;
        *(u16x8*)(abuf + off + 256) = a1;
        if (j < 2) {
            float tx = tg[g], ty = tg[g+1], tz = tg[g+2];
            float dx = x - tx, dy = y - ty, dz = z - tz;
            e = sqrtf(fmaf(dz, dz, fmaf(dy, dy, dx*dx)));
        }
    }
    __syncthreads();

    const int lane = tid & 63, w = tid >> 6;
    const int c = lane & 31, q = lane >> 5;
    const int fo = q * 256 + c * 8;
    const s16x8 fa = *(const s16x8*)(abuf + w * 512 + fo);

    float rm[16];
    #pragma unroll
    for (int i = 0; i < 16; ++i) rm[i] = 3e38f;
    const f32x16 zacc = {};

    const unsigned short* Yp = ybuf + fo;
    #pragma unroll 1
    for (int t = 0; t < 32; t += 2) {
        const s16x8 bb0 = *(const s16x8*)(Yp + t * 512);
        const s16x8 bb1 = *(const s16x8*)(Yp + t * 512 + 512);
        f32x16 u0 = __builtin_amdgcn_mfma_f32_32x32x16_bf16(fa, bb0, zacc, 0, 0, 0);
        f32x16 u1 = __builtin_amdgcn_mfma_f32_32x32x16_bf16(fa, bb1, zacc, 0, 0, 0);
        #pragma unroll
        for (int i = 0; i < 16; ++i) rm[i] = fminf(rm[i], fminf(u0[i], u1[i]));
    }

    const float s = 0.5f * fold_sum(rm, lane);   // sum of sqrt(min) over wave's 32 rows
    #pragma unroll
    for (int mask = 1; mask <= 32; mask <<= 1) e += __shfl_xor(e, mask);
    if (lane == 0) { red[w] = s; redE[w] = e; }
    __syncthreads();

    if (tid == 0) {
        float S = 0.f, E = 0.f;
        #pragma unroll
        for (int k = 0; k < 8; ++k) { S += red[k]; E += redE[k]; }
        ws[bid] = S;
        if (j < 2) ws[1024 + bid] = E;
    }
}

__global__ __launch_bounds__(64) void finalize_kernel(
    const float* __restrict__ flag1, const float* __restrict__ flag2,
    const float* __restrict__ symf, const float* __restrict__ ws,
    float* __restrict__ out)
{
    const int b = threadIdx.x;   // 64 threads, one batch each
    float rowS1 = 0.f, rowS2 = 0.f, colS1 = 0.f, colS2 = 0.f, E1 = 0.f, E2 = 0.f;
    #pragma unroll
    for (int qt = 0; qt < 4; ++qt) {
        rowS1 += ws[0*256 + b*4 + qt];
        rowS2 += ws[1*256 + b*4 + qt];
        colS1 += ws[2*256 + b*4 + qt];
        colS2 += ws[3*256 + b*4 + qt];
        E1    += ws[1024 + 0*256 + b*4 + qt];
        E2    += ws[1024 + 1*256 + b*4 + qt];
    }
    const float inv = 1.f / (float)NPTS;
    const float ch1 = 0.5f * (rowS1 + colS1) * inv;
    const float ch2 = 0.5f * (rowS2 + colS2) * inv;
    const float sf = symf[b];
    float l1 = flag1[b] * (sf * ch1 + (1.f - sf) * E1 * inv);
    float l2 = flag2[b] * (sf * ch2 + (1.f - sf) * E2 * inv);
    #pragma unroll
    for (int mask = 1; mask <= 32; mask <<= 1) {
        l1 += __shfl_xor(l1, mask);
        l2 += __shfl_xor(l2, mask);
    }
    if (b == 0) {
        const float s = 1.f / (float)BATCH;
        out[0] = (l1 + l2) * s;
        out[1] = l1 * s;
        out[2] = l2 * s;
    }
}

extern "C" void kernel_launch(void* const* d_in, const int* in_sizes, int n_in,
                              void* d_out, int out_size, void* d_ws, size_t ws_size,
                              hipStream_t stream) {
    const float* p1 = (const float*)d_in[0];
    const float* p2 = (const float*)d_in[1];
    const float* tg = (const float*)d_in[2];
    const float* f1 = (const float*)d_in[3];
    const float* f2 = (const float*)d_in[4];
    const float* sf = (const float*)d_in[5];
    float* out = (float*)d_out;
    float* ws = (float*)d_ws;   // 1536 floats used; all read slots written every call

    pass_kernel<<<1024, 512, 0, stream>>>(p1, p2, tg, ws);
    finalize_kernel<<<1, 64, 0, stream>>>(f1, f2, sf, ws, out);
}

// Round 7
// 74.041 us; speedup vs baseline: 1.5252x; 1.0293x over previous
//
#include <hip/hip_runtime.h>
#include <hip/hip_bf16.h>

// B=64, N=M=1024, 3-D. Chamfer + slot-L2 loss, 3 scalars.
// d^2 on MFMA 32x32x16 bf16, split-bf16 Gram pack (validated R4-R6):
//   A(point a, c=-2a): [c_hi3, c_lo3, c_hi3, h_hi, h_lo, 1, 1, 0,0,0]
//   B(point b):        [b_hi3, b_hi3, b_lo3, 1, 1, h_hi, h_lo, 0,0,0]
// Split is TRUNCATION-based (bit ops): hi = trunc16(x), lo = trunc16(x - hi);
// residual error ~2^-17 relative, far below the 2.1e-2 threshold.
// Grid = 4 jobs x 64 batches x 2 halves = 512 blocks x 512 threads.
// Each wave owns TWO 32-row A-tiles; one B-frag read feeds two MFMAs.
// jobs: 0: P1 rows vs T | 1: P2 vs T | 2: T vs P1 | 3: T vs P2.

#define BATCH 64
#define NPTS 1024

typedef __attribute__((ext_vector_type(8))) short s16x8;
typedef __attribute__((ext_vector_type(8))) unsigned short u16x8;
typedef __attribute__((ext_vector_type(16))) float f32x16;

__device__ inline void split_bf(float v, unsigned short& hi, unsigned short& lo) {
    unsigned int bits = __float_as_uint(v);
    hi = (unsigned short)(bits >> 16);
    float rec = __uint_as_float(bits & 0xFFFF0000u);
    lo = (unsigned short)(__float_as_uint(v - rec) >> 16);
}

__device__ inline void pack_ab(float x, float y, float z,
                               u16x8& a0, u16x8& a1, u16x8& b0, u16x8& b1) {
    float h = fmaf(z, z, fmaf(y, y, x*x));
    unsigned short xh, xl, yh, yl, zh, zl;
    split_bf(x, xh, xl); split_bf(y, yh, yl); split_bf(z, zh, zl);
    unsigned short cxh, cxl, cyh, cyl, czh, czl;
    split_bf(-2.f*x, cxh, cxl); split_bf(-2.f*y, cyh, cyl); split_bf(-2.f*z, czh, czl);
    unsigned short hh, hl;
    split_bf(h, hh, hl);
    const unsigned short one = 0x3F80;
    a0 = u16x8{cxh, cyh, czh, cxl, cyl, czl, cxh, cyh};
    a1 = u16x8{czh, hh, hl, one, one, 0, 0, 0};
    b0 = u16x8{xh, yh, zh, xh, yh, zh, xl, yl};
    b1 = u16x8{zl, one, one, hh, hl, 0, 0, 0};
}

// Register-halving min-fold over the 32-col group, then sqrt + full-wave sum.
// Returns 2x (sum over the wave's 32 rows of sqrt(max(min,0))). Validated R5/R6.
__device__ inline float fold_sum(float v[16], int lane) {
    {
        const bool up = lane & 1;
        #pragma unroll
        for (int k = 0; k < 8; ++k) {
            float send = up ? v[k] : v[k+8];
            float recv = __shfl_xor(send, 1);
            v[k] = fminf(up ? v[k+8] : v[k], recv);
        }
    }
    {
        const bool up = lane & 2;
        #pragma unroll
        for (int k = 0; k < 4; ++k) {
            float send = up ? v[k] : v[k+4];
            float recv = __shfl_xor(send, 2);
            v[k] = fminf(up ? v[k+4] : v[k], recv);
        }
    }
    {
        const bool up = lane & 4;
        #pragma unroll
        for (int k = 0; k < 2; ++k) {
            float send = up ? v[k] : v[k+2];
            float recv = __shfl_xor(send, 4);
            v[k] = fminf(up ? v[k+2] : v[k], recv);
        }
    }
    {
        const bool up = lane & 8;
        float send = up ? v[0] : v[1];
        float recv = __shfl_xor(send, 8);
        v[0] = fminf(up ? v[1] : v[0], recv);
    }
    v[0] = fminf(v[0], __shfl_xor(v[0], 16));
    float d = sqrtf(fmaxf(v[0], 0.f));
    #pragma unroll
    for (int mask = 1; mask <= 32; mask <<= 1) d += __shfl_xor(d, mask);
    return d;   // each row counted twice
}

__global__ __launch_bounds__(512) void pass_kernel(
    const float* __restrict__ p1, const float* __restrict__ p2,
    const float* __restrict__ tg, float* __restrict__ ws)
{
    __shared__ __align__(16) unsigned short ybuf[16384];  // 32 KB: Y B-pack, whole batch
    __shared__ __align__(16) unsigned short abuf[8192];   // 16 KB: X A-pack, owned half
    __shared__ float red[8];
    __shared__ float redE[8];

    const int bid = blockIdx.x;
    const int j = bid >> 7, b = (bid >> 1) & 63, half = bid & 1;
    const int tid = threadIdx.x;

    const float* __restrict__ X = (j == 0) ? p1 : (j == 1) ? p2 : tg;
    const float* __restrict__ Y = (j == 2) ? p1 : (j == 3) ? p2 : tg;

    // pack Y (B-side): 2 points per thread
    #pragma unroll
    for (int ii = 0; ii < 2; ++ii) {
        const int i = tid + ii * 512;
        const size_t g = ((size_t)b * NPTS + i) * 3;
        float x = Y[g], y = Y[g+1], z = Y[g+2];
        u16x8 a0, a1, b0, b1;
        pack_ab(x, y, z, a0, a1, b0, b1);
        const int off = (i >> 5) * 512 + (i & 31) * 8;
        *(u16x8*)(ybuf + off)       = b0;
        *(u16x8*)(ybuf + off + 256) = b1;
    }
    // pack X half (A-side), 1 point per thread, + slot-L2 term (jobs 0,1)
    float e = 0.f;
    {
        const int i = half * 512 + tid;
        const size_t g = ((size_t)b * NPTS + i) * 3;
        float x = X[g], y = X[g+1], z = X[g+2];
        u16x8 a0, a1, b0, b1;
        pack_ab(x, y, z, a0, a1, b0, b1);
        const int off = (tid >> 5) * 512 + (tid & 31) * 8;
        *(u16x8*)(abuf + off)       = a0;
        *(u16x8*)(abuf + off + 256) = a1;
        if (j < 2) {
            float tx = tg[g], ty = tg[g+1], tz = tg[g+2];
            float dx = x - tx, dy = y - ty, dz = z - tz;
            e = sqrtf(fmaf(dz, dz, fmaf(dy, dy, dx*dx)));
        }
    }
    __syncthreads();

    const int lane = tid & 63, w = tid >> 6;
    const int c = lane & 31, q = lane >> 5;
    const int fo = q * 256 + c * 8;
    // wave owns row-tiles 2w and 2w+1
    const s16x8 fa0 = *(const s16x8*)(abuf + (2*w)   * 512 + fo);
    const s16x8 fa1 = *(const s16x8*)(abuf + (2*w+1) * 512 + fo);

    float rm0[16], rm1[16];
    #pragma unroll
    for (int i = 0; i < 16; ++i) { rm0[i] = 3e38f; rm1[i] = 3e38f; }
    const f32x16 zacc = {};

    const unsigned short* Yp = ybuf + fo;
    #pragma unroll 2
    for (int t = 0; t < 32; ++t) {
        const s16x8 bb = *(const s16x8*)(Yp + t * 512);
        f32x16 u0 = __builtin_amdgcn_mfma_f32_32x32x16_bf16(fa0, bb, zacc, 0, 0, 0);
        f32x16 u1 = __builtin_amdgcn_mfma_f32_32x32x16_bf16(fa1, bb, zacc, 0, 0, 0);
        #pragma unroll
        for (int i = 0; i < 16; ++i) {
            rm0[i] = fminf(rm0[i], u0[i]);
            rm1[i] = fminf(rm1[i], u1[i]);
        }
    }

    // sum over the wave's 64 rows of sqrt(min d^2)
    const float s = 0.5f * (fold_sum(rm0, lane) + fold_sum(rm1, lane));
    #pragma unroll
    for (int mask = 1; mask <= 32; mask <<= 1) e += __shfl_xor(e, mask);
    if (lane == 0) { red[w] = s; redE[w] = e; }
    __syncthreads();

    if (tid == 0) {
        float S = 0.f, E = 0.f;
        #pragma unroll
        for (int k = 0; k < 8; ++k) { S += red[k]; E += redE[k]; }
        ws[bid] = S;                       // 512 S slots
        if (j < 2) ws[512 + bid] = E;      // E slots for jobs 0,1 (bid < 256)
    }
}

__global__ __launch_bounds__(64) void finalize_kernel(
    const float* __restrict__ flag1, const float* __restrict__ flag2,
    const float* __restrict__ symf, const float* __restrict__ ws,
    float* __restrict__ out)
{
    const int b = threadIdx.x;   // 64 threads, one batch each
    float rowS1 = 0.f, rowS2 = 0.f, colS1 = 0.f, colS2 = 0.f, E1 = 0.f, E2 = 0.f;
    #pragma unroll
    for (int h = 0; h < 2; ++h) {
        rowS1 += ws[0*128 + b*2 + h];
        rowS2 += ws[1*128 + b*2 + h];
        colS1 += ws[2*128 + b*2 + h];
        colS2 += ws[3*128 + b*2 + h];
        E1    += ws[512 + 0*128 + b*2 + h];
        E2    += ws[512 + 1*128 + b*2 + h];
    }
    const float inv = 1.f / (float)NPTS;
    const float ch1 = 0.5f * (rowS1 + colS1) * inv;
    const float ch2 = 0.5f * (rowS2 + colS2) * inv;
    const float sf = symf[b];
    float l1 = flag1[b] * (sf * ch1 + (1.f - sf) * E1 * inv);
    float l2 = flag2[b] * (sf * ch2 + (1.f - sf) * E2 * inv);
    #pragma unroll
    for (int mask = 1; mask <= 32; mask <<= 1) {
        l1 += __shfl_xor(l1, mask);
        l2 += __shfl_xor(l2, mask);
    }
    if (b == 0) {
        const float s = 1.f / (float)BATCH;
        out[0] = (l1 + l2) * s;
        out[1] = l1 * s;
        out[2] = l2 * s;
    }
}

extern "C" void kernel_launch(void* const* d_in, const int* in_sizes, int n_in,
                              void* d_out, int out_size, void* d_ws, size_t ws_size,
                              hipStream_t stream) {
    const float* p1 = (const float*)d_in[0];
    const float* p2 = (const float*)d_in[1];
    const float* tg = (const float*)d_in[2];
    const float* f1 = (const float*)d_in[3];
    const float* f2 = (const float*)d_in[4];
    const float* sf = (const float*)d_in[5];
    float* out = (float*)d_out;
    float* ws = (float*)d_ws;   // 768 floats used; every read slot written each call

    pass_kernel<<<512, 512, 0, stream>>>(p1, p2, tg, ws);
    finalize_kernel<<<1, 64, 0, stream>>>(f1, f2, sf, ws, out);
}